// Round 2
// baseline (1165.981 us; speedup 1.0000x reference)
//
#include <hip/hip_runtime.h>
#include <hip/hip_bf16.h>

typedef unsigned short ushort_t;
typedef unsigned int uint_t;
typedef __attribute__((ext_vector_type(8))) short short8;
typedef __attribute__((ext_vector_type(4))) float float4v;

#define K_TOT 256
#define BK 64
#define LDT 72    // LDS row stride (elems) for A/B bf16 tiles: 144B, 16B-aligned rows

__device__ __forceinline__ float bf2f(ushort_t u) {
    union { uint_t i; float f; } c; c.i = ((uint_t)u) << 16; return c.f;
}
__device__ __forceinline__ ushort_t f2bf(float f) {
    union { float f; uint_t i; } c; c.f = f;
    uint_t x = c.i;
    uint_t r = x + 0x7fffu + ((x >> 16) & 1u);   // RNE
    return (ushort_t)(r >> 16);
}
__device__ __forceinline__ float ldv(float x) { return x; }
__device__ __forceinline__ float ldv(ushort_t u) { return bf2f(u); }

// ---------------- graph setup: counting sort by dst ----------------
__global__ void hist_kernel(const int* __restrict__ dstv, int* __restrict__ cnt, int E) {
    int e = blockIdx.x * 256 + threadIdx.x;
    if (e < E) atomicAdd(&cnt[dstv[e]], 1);
}

__global__ void scan_kernel(const int* __restrict__ cnt, int* __restrict__ rowptr,
                            int* __restrict__ cursor, float* __restrict__ deginv, int n) {
    __shared__ int buf[256];
    __shared__ int carry_s;
    int t = threadIdx.x;
    if (t == 0) carry_s = 0;
    __syncthreads();
    for (int base = 0; base < n; base += 256) {
        int i = base + t;
        int v = (i < n) ? cnt[i] : 0;
        buf[t] = v;
        __syncthreads();
        int x = v;
        for (int off = 1; off < 256; off <<= 1) {
            int add = (t >= off) ? buf[t - off] : 0;
            __syncthreads();
            x += add;
            buf[t] = x;
            __syncthreads();
        }
        int carry = carry_s;
        int incl = x + carry;
        if (i < n) {
            rowptr[i] = incl - v;
            cursor[i] = incl - v;
            deginv[i] = 1.0f / (float)(v > 0 ? v : 1);
        }
        __syncthreads();
        if (t == 255) carry_s = incl;
        __syncthreads();
    }
    if (t == 0) rowptr[n] = carry_s;
}

__global__ void scatter_kernel(const int* __restrict__ srcv, const int* __restrict__ dstv,
                               int* __restrict__ cursor, int* __restrict__ srcs_sorted, int E) {
    int e = blockIdx.x * 256 + threadIdx.x;
    if (e < E) {
        int p = atomicAdd(&cursor[dstv[e]], 1);
        srcs_sorted[p] = srcv[e];
    }
}

// ---------------- aggregation fused with Acat build ----------------
// Acat[n][0:128]   = bf16( mean of act[src] over in-edges of n )   (fp32 math)
// Acat[n][128:256] = bf16( act[n] )
template <typename TIN>
__global__ __launch_bounds__(128) void aggregate_kernel(
    const TIN* __restrict__ act, const int* __restrict__ srcs,
    const int* __restrict__ rowptr, const float* __restrict__ deginv,
    ushort_t* __restrict__ Acat) {
    int n = blockIdx.x;
    int f = threadIdx.x;   // 0..127
    int e0 = rowptr[n], e1 = rowptr[n + 1];
    float acc = 0.f;
    int e = e0;
    for (; e + 3 < e1; e += 4) {
        int s0 = srcs[e], s1 = srcs[e + 1], s2 = srcs[e + 2], s3 = srcs[e + 3];
        acc += ldv(act[(size_t)s0 * 128 + f]) + ldv(act[(size_t)s1 * 128 + f]) +
               ldv(act[(size_t)s2 * 128 + f]) + ldv(act[(size_t)s3 * 128 + f]);
    }
    for (; e < e1; e++) acc += ldv(act[(size_t)srcs[e] * 128 + f]);
    Acat[(size_t)n * 256 + f]       = f2bf(acc * deginv[n]);
    Acat[(size_t)n * 256 + 128 + f] = f2bf(ldv(act[(size_t)n * 128 + f]));
}

// ---------------- GEMM ----------------
// C[i][j] = relu( sum_k Ae(i,k)*Be(k,j) + bias ), K = 256, fp32 out, bf16 MFMA.
// TO=false: i = nodes, j in [0,Nout).  Ae = X (Acat bf16, row-major),
//           Be(k,j) = Wcat[k][j] (fp32, transpose-staged->bf16), bias per col j.
// TO=true : i = Nout dim (rows of s^T), j = nodes.  Ae(i,k) = Wcat[k][i]
//           (transpose-staged), Be(k,j) = X[j][k] (row-major), bias per row i.
// Wcat row k: k<128 -> W0[k][.], else W1[k-128][.]  (both [128 x Nout] fp32 row-major)
template <int BM, bool TO>
__global__ __launch_bounds__(256) void gemm_kernel(
    const ushort_t* __restrict__ X, const float* __restrict__ W0,
    const float* __restrict__ W1, const float* __restrict__ bias,
    float* __restrict__ C, int Mnodes, int Nout) {
    constexpr int MT = BM / 32;             // m-tiles per wave
    const int Mi  = TO ? Nout : Mnodes;
    const int Nj  = TO ? Mnodes : Nout;
    const int ldc = Nj;
    const int i0  = blockIdx.x * BM;
    const int j0  = blockIdx.y * 128;

    __shared__ __align__(16) ushort_t smem[256 * LDT];  // 36,864 B
    ushort_t* Alds = smem;                // [BM][LDT]
    ushort_t* Blds = smem + BM * LDT;     // [128][LDT]

    const int tid  = threadIdx.x;
    const int lane = tid & 63;
    const int wid  = tid >> 6;
    const int wm   = wid >> 1, wn = wid & 1;
    const int r16  = lane & 15, quad = lane >> 4;

    float4v acc[MT][4];
#pragma unroll
    for (int a = 0; a < MT; a++)
#pragma unroll
        for (int b = 0; b < 4; b++) acc[a][b] = (float4v){0.f, 0.f, 0.f, 0.f};

    for (int kt = 0; kt < K_TOT / BK; kt++) {
        const int k0 = kt * BK;
        __syncthreads();
        // ---- stage row-major bf16 operand from X (Acat) ----
        {
            const int R = TO ? 128 : BM;
            ushort_t* dst = TO ? Blds : Alds;
            const int base0 = TO ? j0 : i0;
            const int kc = (tid & 7) * 8;
            const int rr0 = tid >> 3;
            for (int r = rr0; r < R; r += 32) {
                short8 v = (short8){0, 0, 0, 0, 0, 0, 0, 0};
                int g = base0 + r;
                if (g < Mnodes)
                    v = *(const short8*)(X + (size_t)g * K_TOT + k0 + kc);
                *(short8*)(dst + r * LDT + kc) = v;
            }
        }
        // ---- stage transposed fp32 operand from Wcat, converting to bf16 ----
        {
            const float* Wt = (k0 < 128) ? (W0 + (size_t)k0 * Nout)
                                         : (W1 + (size_t)(k0 - 128) * Nout);
            ushort_t* dst = TO ? Alds : Blds;
            const int base0 = TO ? i0 : j0;
            const int c2 = (tid & 63) * 2;
            const int kk = tid >> 6;   // 0..3
            const int g = base0 + c2;
            const bool ok = (g < Nout);   // pair-safe: Nout, g both even
#pragma unroll
            for (int k = kk; k < BK; k += 4) {
                float a0 = 0.f, a1 = 0.f;
                if (ok) {
                    const float* wp = Wt + (size_t)k * Nout + g;
                    a0 = wp[0];
                    a1 = wp[1];
                }
                dst[(c2 + 0) * LDT + k] = f2bf(a0);
                dst[(c2 + 1) * LDT + k] = f2bf(a1);
            }
        }
        __syncthreads();
        // ---- MFMA ----
#pragma unroll
        for (int ks = 0; ks < 2; ks++) {
            const int kofs = ks * 32 + quad * 8;
            short8 af[MT], bfr[4];
#pragma unroll
            for (int im = 0; im < MT; im++)
                af[im] = *(const short8*)(Alds + (wm * (BM / 2) + im * 16 + r16) * LDT + kofs);
#pragma unroll
            for (int jn = 0; jn < 4; jn++)
                bfr[jn] = *(const short8*)(Blds + (wn * 64 + jn * 16 + r16) * LDT + kofs);
#pragma unroll
            for (int im = 0; im < MT; im++)
#pragma unroll
                for (int jn = 0; jn < 4; jn++)
                    acc[im][jn] = __builtin_amdgcn_mfma_f32_16x16x32_bf16(
                        af[im], bfr[jn], acc[im][jn], 0, 0, 0);
        }
    }

    // ---- epilogue: bias + relu, direct fp32 stores ----
    const int rows_lim = Mi - i0;
    const int cols_lim = Nj - j0;
#pragma unroll
    for (int im = 0; im < MT; im++) {
#pragma unroll
        for (int jn = 0; jn < 4; jn++) {
            const int jl = wn * 64 + jn * 16 + r16;
            const bool jok = (jl < cols_lim);
#pragma unroll
            for (int r = 0; r < 4; r++) {
                const int il = wm * (BM / 2) + im * 16 + quad * 4 + r;
                const int bidx = TO ? (i0 + il) : (j0 + jl);
                const float bv = (bidx < Nout) ? bias[bidx] : 0.f;
                float v = acc[im][jn][r] + bv;
                v = fmaxf(v, 0.f);
                if (jok && il < rows_lim)
                    C[(size_t)(i0 + il) * ldc + (j0 + jl)] = v;
            }
        }
    }
}

// ---------------- host launch ----------------
extern "C" void kernel_launch(void* const* d_in, const int* in_sizes, int n_in,
                              void* d_out, int out_size, void* d_ws, size_t ws_size,
                              hipStream_t stream) {
    const int N = in_sizes[18];       // bl_s2 length == num nodes
    const int E = in_sizes[1] / 2;

    const float* x = (const float*)d_in[0];
    const int* ei = (const int*)d_in[1];
    const int* srcv = ei;
    const int* dstv = ei + E;

    const float* Wl[6] = {(const float*)d_in[2],  (const float*)d_in[5],
                          (const float*)d_in[8],  (const float*)d_in[11],
                          (const float*)d_in[14], (const float*)d_in[17]};
    const float* bl[6] = {(const float*)d_in[3],  (const float*)d_in[6],
                          (const float*)d_in[9],  (const float*)d_in[12],
                          (const float*)d_in[15], (const float*)d_in[18]};
    const float* Wr[6] = {(const float*)d_in[4],  (const float*)d_in[7],
                          (const float*)d_in[10], (const float*)d_in[13],
                          (const float*)d_in[16], (const float*)d_in[19]};

    // workspace carve (~12 MB)
    char* p = (char*)d_ws;
    auto carve = [&](size_t bytes) -> char* {
        char* q = p;
        p += (bytes + 255) & ~(size_t)255;
        return q;
    };
    int*      cnt    = (int*)carve((size_t)N * 4);
    int*      rowptr = (int*)carve((size_t)(N + 1) * 4);
    int*      cursor = (int*)carve((size_t)N * 4);
    float*    deginv = (float*)carve((size_t)N * 4);
    int*      srcs   = (int*)carve((size_t)E * 4);
    ushort_t* actA   = (ushort_t*)carve((size_t)N * 128 * 2);
    ushort_t* actB   = (ushort_t*)carve((size_t)N * 128 * 2);
    ushort_t* Acat   = (ushort_t*)carve((size_t)N * 256 * 2);
    float*    actFA  = (float*)carve((size_t)N * 128 * 4);
    float*    actFB  = (float*)carve((size_t)N * 128 * 4);

    hipMemsetAsync(cnt, 0, (size_t)N * 4, stream);
    hist_kernel<<<(E + 255) / 256, 256, 0, stream>>>(dstv, cnt, E);
    scan_kernel<<<1, 256, 0, stream>>>(cnt, rowptr, cursor, deginv, N);
    scatter_kernel<<<(E + 255) / 256, 256, 0, stream>>>(srcv, dstv, cursor, srcs, E);

    float* outp = (float*)d_out;
    float* xh_out = outp + (size_t)N * N;

    auto layer = [&](const float* act_in_f, int li, float* out) {
        if (act_in_f)
            aggregate_kernel<float><<<N, 128, 0, stream>>>(act_in_f, srcs, rowptr, deginv, Acat);
        gemm_kernel<64, false><<<dim3((N + 63) / 64, 1), 256, 0, stream>>>(
            Acat, Wl[li], Wr[li], bl[li], out, N, 128);
    };

    layer(x,     0, actFA);    // e1: x -> h1        (fp32 activations)
    layer(actFA, 1, actFB);    // e2: h1 -> h
    layer(actFB, 2, actFA);    // a1: h -> a1out
    layer(actFA, 3, xh_out);   // a2: a1out -> xh (direct to d_out)
    layer(actFB, 4, actFA);    // s1: h -> s1out

    // s2: s1out -> s^T, transposed output folded into GEMM (TO=true)
    aggregate_kernel<float><<<N, 128, 0, stream>>>(actFA, srcs, rowptr, deginv, Acat);
    gemm_kernel<128, true><<<dim3((N + 127) / 128, (N + 127) / 128), 256, 0, stream>>>(
        Acat, Wl[5], Wr[5], bl[5], outp, N, N);

    (void)actA; (void)actB; (void)n_in; (void)out_size; (void)ws_size;
}

// Round 3
// 833.688 us; speedup vs baseline: 1.3986x; 1.3986x over previous
//
#include <hip/hip_runtime.h>
#include <hip/hip_bf16.h>

typedef unsigned short ushort_t;
typedef unsigned int uint_t;
typedef __attribute__((ext_vector_type(8))) short short8;
typedef __attribute__((ext_vector_type(4))) float float4v;

__device__ __forceinline__ float bf2f(ushort_t u) {
    union { uint_t i; float f; } c; c.i = ((uint_t)u) << 16; return c.f;
}
__device__ __forceinline__ ushort_t f2bf(float f) {
    union { float f; uint_t i; } c; c.f = f;
    uint_t x = c.i;
    uint_t r = x + 0x7fffu + ((x >> 16) & 1u);   // RNE
    return (ushort_t)(r >> 16);
}

// async global->LDS, 16B per lane; LDS dest = wave-uniform base + lane*16
__device__ __forceinline__ void gl_lds16(const void* g, void* l) {
    __builtin_amdgcn_global_load_lds(
        (const __attribute__((address_space(1))) void*)g,
        (__attribute__((address_space(3))) void*)l, 16, 0, 0);
}

__device__ __forceinline__ void stv(float* p, float v) { *p = v; }
__device__ __forceinline__ void stv(ushort_t* p, float v) { *p = f2bf(v); }

// ---------------- graph setup: counting sort by dst ----------------
__global__ void hist_kernel(const int* __restrict__ dstv, int* __restrict__ cnt, int E) {
    int e = blockIdx.x * 256 + threadIdx.x;
    if (e < E) atomicAdd(&cnt[dstv[e]], 1);
}

// one block, 1024 threads: chunked scan (PER<=16 -> n<=16384)
__global__ __launch_bounds__(1024) void scan_kernel(
    const int* __restrict__ cnt, int* __restrict__ rowptr,
    int* __restrict__ cursor, float* __restrict__ deginv, int n) {
    __shared__ int sums[1024];
    const int t = threadIdx.x;
    const int per = (n + 1023) >> 10;
    const int b0 = t * per;
    int s = 0;
    for (int u = 0; u < per; u++) {
        int i = b0 + u;
        if (i < n) s += cnt[i];
    }
    sums[t] = s;
    __syncthreads();
    int x = s;
    for (int off = 1; off < 1024; off <<= 1) {
        int y = (t >= off) ? sums[t - off] : 0;
        __syncthreads();
        x += y;
        sums[t] = x;
        __syncthreads();
    }
    int run = x - s;   // exclusive prefix of this thread's chunk
    for (int u = 0; u < per; u++) {
        int i = b0 + u;
        if (i < n) {
            int v = cnt[i];
            rowptr[i] = run;
            cursor[i] = run;
            deginv[i] = 1.0f / (float)(v > 0 ? v : 1);
            run += v;
        }
    }
    if (t == 1023) rowptr[n] = x;
}

__global__ void scatter_kernel(const int* __restrict__ srcv, const int* __restrict__ dstv,
                               int* __restrict__ cursor, int* __restrict__ srcs_sorted, int E) {
    int e = blockIdx.x * 256 + threadIdx.x;
    if (e < E) {
        int p = atomicAdd(&cursor[dstv[e]], 1);
        srcs_sorted[p] = srcv[e];
    }
}

// ---------------- weight transpose: WT[i][k] = bf16(Wcat[k][i]) ----------------
// Wcat row k: k<128 -> W0[k][.], else W1[k-128][.]; WT is [Nout][256] bf16.
__global__ __launch_bounds__(256) void transpose_w_kernel(
    const float* __restrict__ W0, const float* __restrict__ W1,
    ushort_t* __restrict__ WT, int Nout) {
    __shared__ ushort_t tile[64][72];
    const int i0 = blockIdx.x * 64;
    const int k0 = blockIdx.y * 64;
    const float* W = (k0 < 128) ? (W0 + (size_t)k0 * Nout)
                                : (W1 + (size_t)(k0 - 128) * Nout);
    const int tid = threadIdx.x;
    const int li = tid & 63;
    const int kq = tid >> 6;
    const int gi = i0 + li;
    const bool ok = gi < Nout;
    for (int k = kq; k < 64; k += 4) {
        float v = ok ? W[(size_t)k * Nout + gi] : 0.f;
        tile[li][k] = f2bf(v);
    }
    __syncthreads();
    for (int s = tid; s < 512; s += 256) {
        int r = s >> 3, ch = s & 7;
        int gi2 = i0 + r;
        if (gi2 < Nout)
            *(short8*)(WT + (size_t)gi2 * 256 + k0 + ch * 8) = *(const short8*)&tile[r][ch * 8];
    }
}

// ---------------- aggregation (wave per node) ----------------
// Acat[n][0:128] = bf16(mean of act[src]); Acat[n][128:256] = bf16(act[n])
template <typename TIN>
__device__ __forceinline__ float2 ld2(const TIN* act, size_t row, int t);
template <>
__device__ __forceinline__ float2 ld2<float>(const float* act, size_t row, int t) {
    return ((const float2*)act)[row * 64 + t];
}
template <>
__device__ __forceinline__ float2 ld2<ushort_t>(const ushort_t* act, size_t row, int t) {
    uint_t u = ((const uint_t*)act)[row * 64 + t];
    float2 r; r.x = bf2f((ushort_t)(u & 0xffffu)); r.y = bf2f((ushort_t)(u >> 16));
    return r;
}

template <typename TIN>
__global__ __launch_bounds__(256) void aggregate_kernel(
    const TIN* __restrict__ act, const int* __restrict__ srcs,
    const int* __restrict__ rowptr, const float* __restrict__ deginv,
    ushort_t* __restrict__ Acat, int N) {
    int node = blockIdx.x * 4 + (threadIdx.x >> 6);
    if (node >= N) return;
    int t = threadIdx.x & 63;
    int e0 = rowptr[node], e1 = rowptr[node + 1];
    float ax = 0.f, ay = 0.f;
    int e = e0;
    for (; e + 4 <= e1; e += 4) {
        int s0 = srcs[e], s1 = srcs[e + 1], s2 = srcs[e + 2], s3 = srcs[e + 3];
        float2 v0 = ld2(act, (size_t)s0, t);
        float2 v1 = ld2(act, (size_t)s1, t);
        float2 v2 = ld2(act, (size_t)s2, t);
        float2 v3 = ld2(act, (size_t)s3, t);
        ax += v0.x + v1.x + v2.x + v3.x;
        ay += v0.y + v1.y + v2.y + v3.y;
    }
    for (; e < e1; e++) {
        float2 v = ld2(act, (size_t)srcs[e], t);
        ax += v.x; ay += v.y;
    }
    float dinv = deginv[node];
    uint_t m = ((uint_t)f2bf(ay * dinv) << 16) | (uint_t)f2bf(ax * dinv);
    float2 self = ld2(act, (size_t)node, t);
    uint_t sf = ((uint_t)f2bf(self.y) << 16) | (uint_t)f2bf(self.x);
    ((uint_t*)Acat)[(size_t)node * 128 + t]      = m;
    ((uint_t*)Acat)[(size_t)node * 128 + 64 + t] = sf;
}

// ---------------- NT GEMM: C[i][j] = relu(sum_k A[i][k]*B[j][k] + bias) ----------------
// A:[rowsA][256] bf16, B:[rowsB][256] bf16, C:[rowsA][rowsB] (ldc=rowsB).
// bias indexed by i (BIAS_I) or j. 128x128 tile, BK=64, global_load_lds staging,
// XOR-swizzled LDS chunks, grouped block-order swizzle (GRP=8) for L2 reuse.
template <bool BIAS_I, typename TOUT>
__global__ __launch_bounds__(256) void gemm_nt_kernel(
    const ushort_t* __restrict__ A, const ushort_t* __restrict__ B,
    const float* __restrict__ bias, TOUT* __restrict__ C,
    int rowsA, int rowsB, int tilesM, int tilesN) {
    __shared__ __align__(16) ushort_t Alds[128 * 64];
    __shared__ __align__(16) ushort_t Blds[128 * 64];

    const int lin = blockIdx.x;
    const int GRP = 8;
    const int nig = GRP * tilesN;
    const int gidg = lin / nig;
    const int first_m = gidg * GRP;
    const int gsz = min(tilesM - first_m, GRP);
    const int in_grp = lin - gidg * nig;
    const int pid_m = first_m + (in_grp % gsz);
    const int pid_n = in_grp / gsz;
    const int i0 = pid_m * 128;
    const int j0 = pid_n * 128;

    const int tid  = threadIdx.x;
    const int lane = tid & 63;
    const int wid  = tid >> 6;
    const int wm = wid >> 1, wn = wid & 1;
    const int r16 = lane & 15, quad = lane >> 4;
    const int rsub = lane >> 3;              // row-in-window 0..7
    const int csw  = (lane & 7) ^ rsub;      // swizzled global chunk for staging

    float4v acc[4][4];
#pragma unroll
    for (int a = 0; a < 4; a++)
#pragma unroll
        for (int b = 0; b < 4; b++) acc[a][b] = (float4v){0.f, 0.f, 0.f, 0.f};

    for (int kt = 0; kt < 4; kt++) {
        __syncthreads();
        const int kbase = kt * 64 + csw * 8;
#pragma unroll
        for (int t = 0; t < 4; t++) {
            const int w8 = (wid * 4 + t) * 8;     // first row of this 8-row window
            int rA = min(i0 + w8 + rsub, rowsA - 1);
            gl_lds16(A + (size_t)rA * 256 + kbase, Alds + w8 * 64);
            int rB = min(j0 + w8 + rsub, rowsB - 1);
            gl_lds16(B + (size_t)rB * 256 + kbase, Blds + w8 * 64);
        }
        __syncthreads();   // barrier drains vmcnt -> LDS tiles ready
#pragma unroll
        for (int ks = 0; ks < 2; ks++) {
            const int chb = ks * 4 + quad;
            const int sw = ((chb ^ (r16 & 7))) * 8;
            short8 af[4], bfr[4];
#pragma unroll
            for (int im = 0; im < 4; im++)
                af[im] = *(const short8*)(Alds + (wm * 64 + im * 16 + r16) * 64 + sw);
#pragma unroll
            for (int jn = 0; jn < 4; jn++)
                bfr[jn] = *(const short8*)(Blds + (wn * 64 + jn * 16 + r16) * 64 + sw);
#pragma unroll
            for (int im = 0; im < 4; im++)
#pragma unroll
                for (int jn = 0; jn < 4; jn++)
                    acc[im][jn] = __builtin_amdgcn_mfma_f32_16x16x32_bf16(
                        af[im], bfr[jn], acc[im][jn], 0, 0, 0);
        }
    }

    const int rows_lim = rowsA - i0;
    const int cols_lim = rowsB - j0;
#pragma unroll
    for (int im = 0; im < 4; im++) {
#pragma unroll
        for (int jn = 0; jn < 4; jn++) {
            const int jl = wn * 64 + jn * 16 + r16;
            if (jl < cols_lim) {
#pragma unroll
                for (int r = 0; r < 4; r++) {
                    const int il = wm * 64 + im * 16 + quad * 4 + r;
                    if (il < rows_lim) {
                        float bv = bias[BIAS_I ? (i0 + il) : (j0 + jl)];
                        float v = fmaxf(acc[im][jn][r] + bv, 0.f);
                        stv(C + (size_t)(i0 + il) * rowsB + (j0 + jl), v);
                    }
                }
            }
        }
    }
}

// ---------------- host launch ----------------
extern "C" void kernel_launch(void* const* d_in, const int* in_sizes, int n_in,
                              void* d_out, int out_size, void* d_ws, size_t ws_size,
                              hipStream_t stream) {
    const int N = in_sizes[18];       // bl_s2 length == num nodes
    const int E = in_sizes[1] / 2;

    const float* x = (const float*)d_in[0];
    const int* ei = (const int*)d_in[1];
    const int* srcv = ei;
    const int* dstv = ei + E;

    const float* Wl[6] = {(const float*)d_in[2],  (const float*)d_in[5],
                          (const float*)d_in[8],  (const float*)d_in[11],
                          (const float*)d_in[14], (const float*)d_in[17]};
    const float* bl[6] = {(const float*)d_in[3],  (const float*)d_in[6],
                          (const float*)d_in[9],  (const float*)d_in[12],
                          (const float*)d_in[15], (const float*)d_in[18]};
    const float* Wr[6] = {(const float*)d_in[4],  (const float*)d_in[7],
                          (const float*)d_in[10], (const float*)d_in[13],
                          (const float*)d_in[16], (const float*)d_in[19]};

    char* p = (char*)d_ws;
    auto carve = [&](size_t bytes) -> char* {
        char* q = p;
        p += (bytes + 255) & ~(size_t)255;
        return q;
    };
    int*      cnt    = (int*)carve((size_t)N * 4);
    int*      rowptr = (int*)carve((size_t)(N + 1) * 4);
    int*      cursor = (int*)carve((size_t)N * 4);
    float*    deginv = (float*)carve((size_t)N * 4);
    int*      srcs   = (int*)carve((size_t)E * 4);
    ushort_t* Acat   = (ushort_t*)carve((size_t)N * 256 * 2);
    ushort_t* hbA    = (ushort_t*)carve((size_t)N * 128 * 2);   // bf16 activations
    ushort_t* hbB    = (ushort_t*)carve((size_t)N * 128 * 2);
    ushort_t* WTs2   = (ushort_t*)carve((size_t)N * 256 * 2);   // s2 weights transposed
    ushort_t* WsT    = (ushort_t*)carve((size_t)5 * 128 * 256 * 2);

    hipMemsetAsync(cnt, 0, (size_t)N * 4, stream);
    hist_kernel<<<(E + 255) / 256, 256, 0, stream>>>(dstv, cnt, E);
    scan_kernel<<<1, 1024, 0, stream>>>(cnt, rowptr, cursor, deginv, N);
    scatter_kernel<<<(E + 255) / 256, 256, 0, stream>>>(srcv, dstv, cursor, srcs, E);

    // transpose all weights to [Nout][256] bf16 (Wcat = [Wl; Wr])
    for (int li = 0; li < 5; li++)
        transpose_w_kernel<<<dim3(2, 4), 256, 0, stream>>>(
            Wl[li], Wr[li], WsT + (size_t)li * 128 * 256, 128);
    transpose_w_kernel<<<dim3((N + 63) / 64, 4), 256, 0, stream>>>(
        Wl[5], Wr[5], WTs2, N);

    float* outp = (float*)d_out;
    float* xh_out = outp + (size_t)N * N;

    const int tM = (N + 127) / 128;   // 79

    // e1: x(fp32) -> hbA
    aggregate_kernel<float><<<(N + 3) / 4, 256, 0, stream>>>(x, srcs, rowptr, deginv, Acat, N);
    gemm_nt_kernel<false, ushort_t><<<tM, 256, 0, stream>>>(
        Acat, WsT + 0 * 128 * 256, bl[0], hbA, N, 128, tM, 1);
    // e2: hbA -> hbB (h)
    aggregate_kernel<ushort_t><<<(N + 3) / 4, 256, 0, stream>>>(hbA, srcs, rowptr, deginv, Acat, N);
    gemm_nt_kernel<false, ushort_t><<<tM, 256, 0, stream>>>(
        Acat, WsT + 1 * 128 * 256, bl[1], hbB, N, 128, tM, 1);
    // a1: hbB -> hbA
    aggregate_kernel<ushort_t><<<(N + 3) / 4, 256, 0, stream>>>(hbB, srcs, rowptr, deginv, Acat, N);
    gemm_nt_kernel<false, ushort_t><<<tM, 256, 0, stream>>>(
        Acat, WsT + 2 * 128 * 256, bl[2], hbA, N, 128, tM, 1);
    // a2: hbA -> xh (fp32, direct to d_out)
    aggregate_kernel<ushort_t><<<(N + 3) / 4, 256, 0, stream>>>(hbA, srcs, rowptr, deginv, Acat, N);
    gemm_nt_kernel<false, float><<<tM, 256, 0, stream>>>(
        Acat, WsT + 3 * 128 * 256, bl[3], xh_out, N, 128, tM, 1);
    // s1: hbB -> hbA
    aggregate_kernel<ushort_t><<<(N + 3) / 4, 256, 0, stream>>>(hbB, srcs, rowptr, deginv, Acat, N);
    gemm_nt_kernel<false, ushort_t><<<tM, 256, 0, stream>>>(
        Acat, WsT + 4 * 128 * 256, bl[4], hbA, N, 128, tM, 1);
    // s2: A = WTs2 (i over out-dim), B = Acat (j over nodes), bias on i, C = s^T
    aggregate_kernel<ushort_t><<<(N + 3) / 4, 256, 0, stream>>>(hbA, srcs, rowptr, deginv, Acat, N);
    gemm_nt_kernel<true, float><<<tM * tM, 256, 0, stream>>>(
        WTs2, Acat, bl[5], outp, N, N, tM, tM);

    (void)n_in; (void)out_size; (void)ws_size;
}